// Round 11
// baseline (184.712 us; speedup 1.0000x reference)
//
#include <hip/hip_runtime.h>

#define Bn 16
#define Cn 256
#define HWn 9216
#define Pn 64
#define HEADSn 4
#define Gn 2304
#define STILE 64
#define TILES_PER_B (HWn / STILE)    // 144
#define NTILE (Bn * TILES_PER_B)     // 2304 (k3 logical grid)
#define T32_PER_B 288                // 32-col tiles per batch
#define NBLK1 (Bn * T32_PER_B)       // 4608 k1 logical blocks
#define DUP 2                        // diagnostic duplication factor

typedef float f32x4 __attribute__((ext_vector_type(4)));
typedef short short4v __attribute__((ext_vector_type(4)));
typedef short short8 __attribute__((ext_vector_type(8)));
typedef unsigned int uint2v __attribute__((ext_vector_type(2)));

static __device__ __forceinline__ unsigned short f2bf(float f) {
    unsigned int b = __builtin_bit_cast(unsigned int, f);
    unsigned int r = b + 0x7FFFu + ((b >> 16) & 1u);   // RNE
    return (unsigned short)(r >> 16);
}
static __device__ __forceinline__ float bf2f(unsigned short u) {
    unsigned int b = ((unsigned int)u) << 16;
    return __builtin_bit_cast(float, b);
}
static __device__ __forceinline__ unsigned int cvtpk(float a, float b) {
    unsigned int r;
    asm("v_cvt_pk_bf16_f32 %0, %1, %2" : "=v"(r) : "v"(a), "v"(b));
    return r;
}

// ---- K0: w1 -> bf16 with BN scale folded per row; bc vector ----
__global__ __launch_bounds__(256)
void k0_prep(const float* __restrict__ w1, const float* __restrict__ b1,
             const float* __restrict__ gamma, const float* __restrict__ beta,
             const float* __restrict__ mean, const float* __restrict__ var,
             float* __restrict__ bcv, short* __restrict__ w1b)
{
    const int gid = blockIdx.x * 256 + threadIdx.x;
    if (gid < 2048) {                       // 2048 granules of 8 floats
        const int row = gid >> 5;
        const float s = gamma[row] * rsqrtf(var[row] + 1e-5f);
        const float* p = w1 + gid * 8;
        short8 v;
        #pragma unroll
        for (int j = 0; j < 8; ++j) v[j] = (short)f2bf(p[j] * s);
        *reinterpret_cast<short8*>(&w1b[gid * 8]) = v;
    }
    if (gid < Pn) {
        const float s = gamma[gid] * rsqrtf(var[gid] + 1e-5f);
        bcv[gid] = (b1[gid] - mean[gid]) * s + beta[gid];
    }
}

// ---- K1: identical to round 10, launched at DUP x grid for counter visibility ----
__global__ __launch_bounds__(128, 4)
void k1_gemm(const float* __restrict__ x, const short* __restrict__ w1b,
             const float* __restrict__ bcv, const float* __restrict__ wm,
             float* __restrict__ hmp, short* __restrict__ hg)
{
    __shared__ short xl[Cn * 32];          // 16 KB bf16, swizzled

    const int bid  = blockIdx.x % NBLK1;   // duplicate blocks redo identical work
    const int b    = bid / T32_PER_B;
    const int t32  = bid % T32_PER_B;
    const int s0   = t32 * 32;
    const int t    = threadIdx.x;
    const int lane = t & 63;
    const int wv   = t >> 6;               // 0..1, owns p in [wv*32, wv*32+32)
    const int g    = lane >> 4;
    const int m16  = lane & 15;

    // ---- A-fragments (BN-scale folded) into registers: 64 VGPR ----
    short8 af[2][8];
    #pragma unroll
    for (int rt = 0; rt < 2; ++rt)
        #pragma unroll
        for (int ks = 0; ks < 8; ++ks)
            af[rt][ks] = *reinterpret_cast<const short8*>(
                w1b + (wv * 32 + rt * 16 + m16) * Cn + ks * 32 + g * 8);

    float bc[2][4];
    #pragma unroll
    for (int rt = 0; rt < 2; ++rt)
        #pragma unroll
        for (int r = 0; r < 4; ++r) bc[rt][r] = bcv[wv * 32 + rt * 16 + g * 4 + r];

    // ---- stage x tile: thread (krow=t>>3, chk=t&7); coalesced 128B per 8 lanes ----
    const int krow = t >> 3;
    const int chk  = t & 7;
    const float* xb = x + (size_t)b * Cn * HWn + s0 + chk * 4;
    #pragma unroll
    for (int i = 0; i < 16; ++i) {
        const int k = i * 16 + krow;
        const f32x4 v = *reinterpret_cast<const f32x4*>(xb + (size_t)k * HWn);
        uint2v pk;
        pk[0] = cvtpk(v[0], v[1]);
        pk[1] = cvtpk(v[2], v[3]);
        const int f    = (k ^ (k >> 2)) & 3;
        const int byte = k * 64 + (((chk >> 1) ^ f) * 16) + (chk & 1) * 8;
        *reinterpret_cast<uint2v*>(reinterpret_cast<char*>(xl) + byte) = pk;
    }
    __syncthreads();

    // ---- GEMM1: 8 ks x { 2 cg x (8 bf16 reads + 2 MFMA) } ----
    f32x4 acc[2][2] = { { {0,0,0,0}, {0,0,0,0} }, { {0,0,0,0}, {0,0,0,0} } };
    #pragma unroll
    for (int ks = 0; ks < 8; ++ks) {
        #pragma unroll
        for (int cg = 0; cg < 2; ++cg) {
            short8 bf;
            #pragma unroll
            for (int j = 0; j < 8; ++j) {
                const int k    = ks * 32 + g * 8 + j;
                const int f    = (k ^ (k >> 2)) & 3;
                const int byte = k * 64 + ((((cg * 2) + (m16 >> 3)) ^ f) * 16) + (m16 & 7) * 2;
                bf[j] = *reinterpret_cast<const short*>(
                    reinterpret_cast<const char*>(xl) + byte);
            }
            acc[cg][0] = __builtin_amdgcn_mfma_f32_16x16x32_bf16(af[0][ks], bf, acc[cg][0], 0, 0, 0);
            acc[cg][1] = __builtin_amdgcn_mfma_f32_16x16x32_bf16(af[1][ks], bf, acc[cg][1], 0, 0, 0);
        }
    }

    // ---- bias + ReLU + h store [s][p] + hm register accumulate ----
    const float wmv0 = wm[s0 + m16];
    const float wmv1 = wm[s0 + 16 + m16];
    float hmacc[2][4];
    #pragma unroll
    for (int rt = 0; rt < 2; ++rt)
        #pragma unroll
        for (int r = 0; r < 4; ++r) hmacc[rt][r] = 0.f;

    #pragma unroll
    for (int cg = 0; cg < 2; ++cg) {
        const float wmv = cg ? wmv1 : wmv0;
        short* hrow = hg + ((size_t)b * HWn + s0 + cg * 16 + m16) * Pn + wv * 32;
        #pragma unroll
        for (int rt = 0; rt < 2; ++rt) {
            float h[4];
            #pragma unroll
            for (int r = 0; r < 4; ++r) {
                float hv = acc[cg][rt][r] + bc[rt][r];
                hv = hv > 0.f ? hv : 0.f;
                hmacc[rt][r] = fmaf(hv, wmv, hmacc[rt][r]);
                h[r] = hv;
            }
            uint2v pk;
            pk[0] = cvtpk(h[0], h[1]);
            pk[1] = cvtpk(h[2], h[3]);
            *reinterpret_cast<uint2v*>(hrow + rt * 16 + g * 4) = pk;
        }
    }

    // ---- hm partial: reduce over the 16 s-columns (shfl), store per-block ----
    #pragma unroll
    for (int rt = 0; rt < 2; ++rt)
        #pragma unroll
        for (int r = 0; r < 4; ++r) {
            float v = hmacc[rt][r];
            v += __shfl_xor(v, 1); v += __shfl_xor(v, 2);
            v += __shfl_xor(v, 4); v += __shfl_xor(v, 8);
            hmacc[rt][r] = v;
        }
    if (m16 == 0) {
        #pragma unroll
        for (int rt = 0; rt < 2; ++rt)
            #pragma unroll
            for (int r = 0; r < 4; ++r)
                hmp[bid * Pn + wv * 32 + rt * 16 + g * 4 + r] = hmacc[rt][r];
    }
}

// ---- K2: reduce 72 tile-partials -> logits -> softmax -> wmix/bmix ----
__global__ __launch_bounds__(256)
void k2_mask(const float* __restrict__ hmp, const float* __restrict__ w2,
             const float* __restrict__ b2, const float* __restrict__ wm,
             float* __restrict__ wmix, float* __restrict__ bmix)
{
    __shared__ float hms[Pn];
    __shared__ float masks[Cn];
    __shared__ float red[4];
    __shared__ float part[4][Pn];

    const int bh = blockIdx.x;
    const int head = bh & (HEADSn - 1);
    const int t = threadIdx.x;
    const int l = t & 63;
    const int wv = t >> 6;

    // this (b,head)'s partials: blocks (b*288 + head*72) .. +71
    {
        const int p = t & 63, q = t >> 6;
        const float* base = hmp + ((size_t)(bh >> 2) * T32_PER_B + head * 72) * Pn;
        float sp = 0.f;
        #pragma unroll
        for (int jj = 0; jj < 18; ++jj) sp += base[(q + 4 * jj) * Pn + p];
        part[q][p] = sp;
    }
    __syncthreads();
    if (t < Pn) hms[t] = part[0][t] + part[1][t] + part[2][t] + part[3][t];
    __syncthreads();

    // wmsum over this head's group
    float wsum = 0.f;
    for (int i = t; i < Gn; i += 256) wsum += wm[head * Gn + i];
    #pragma unroll
    for (int d = 1; d < 64; d <<= 1) wsum += __shfl_xor(wsum, d);
    if (l == 0) red[wv] = wsum;
    __syncthreads();
    wsum = red[0] + red[1] + red[2] + red[3];

    // logits[c] = sum_k w2[c,k]*hm[k] + b2[c]*wsum
    float lg = 0.f;
    #pragma unroll
    for (int k = 0; k < Pn; ++k) lg = fmaf(w2[t * Pn + k], hms[k], lg);
    lg = fmaf(b2[t], wsum, lg);

    // softmax over 256 channels
    float mx = lg;
    #pragma unroll
    for (int d = 1; d < 64; d <<= 1) mx = fmaxf(mx, __shfl_xor(mx, d));
    __syncthreads();
    if (l == 0) red[wv] = mx;
    __syncthreads();
    mx = fmaxf(fmaxf(red[0], red[1]), fmaxf(red[2], red[3]));
    const float ev = __expf(lg - mx);
    float sm = ev;
    #pragma unroll
    for (int d = 1; d < 64; d <<= 1) sm += __shfl_xor(sm, d);
    __syncthreads();
    if (l == 0) red[wv] = sm;
    __syncthreads();
    sm = red[0] + red[1] + red[2] + red[3];
    masks[t] = ev / sm;
    __syncthreads();

    // wmix[k] = sum_c mask[c]*w2[c,k]
    {
        const int k = t & (Pn - 1);
        const int q = t >> 6;
        float wp = 0.f;
        #pragma unroll
        for (int i = 0; i < 64; ++i) {
            const int c = q * 64 + i;
            wp = fmaf(masks[c], w2[c * Pn + k], wp);
        }
        part[q][k] = wp;
    }
    __syncthreads();
    if (t < Pn) wmix[bh * Pn + t] = part[0][t] + part[1][t] + part[2][t] + part[3][t];

    // bmix = sum_c mask[c]*b2[c]
    float bp = masks[t] * b2[t];
    #pragma unroll
    for (int d = 1; d < 64; d <<= 1) bp += __shfl_xor(bp, d);
    __syncthreads();
    if (l == 0) red[wv] = bp;
    __syncthreads();
    if (t == 0) bmix[bh] = red[0] + red[1] + red[2] + red[3];
}

// ---- K3: identical to round 10, launched at DUP x grid for counter visibility ----
__global__ __launch_bounds__(256)
void k3_stream(const float* __restrict__ x, const short* __restrict__ hg,
               const float* __restrict__ wmix, const float* __restrict__ bmix,
               float* __restrict__ out)
{
    __shared__ float ctxl[STILE];

    const int bid  = blockIdx.x % NTILE;   // duplicate blocks redo identical work
    const int b    = bid / TILES_PER_B;
    const int tile = bid % TILES_PER_B;
    const int s0   = tile * STILE;
    const int head = s0 / Gn;
    const int bh   = b * HEADSn + head;
    const int t    = threadIdx.x;

    if (t < STILE) {
        const short* hr = hg + ((size_t)b * HWn + s0 + t) * Pn;   // dense 128 B/lane
        const float* wmx = wmix + bh * Pn;
        float acc = 0.f;
        #pragma unroll
        for (int i = 0; i < 8; ++i) {
            const short8 v = *reinterpret_cast<const short8*>(hr + i * 8);
            const f32x4 w0 = *reinterpret_cast<const f32x4*>(wmx + i * 8);
            const f32x4 w1v = *reinterpret_cast<const f32x4*>(wmx + i * 8 + 4);
            #pragma unroll
            for (int j = 0; j < 4; ++j) {
                acc = fmaf(bf2f((unsigned short)v[j]), w0[j], acc);
                acc = fmaf(bf2f((unsigned short)v[4 + j]), w1v[j], acc);
            }
        }
        ctxl[t] = acc + bmix[bh];
    }
    __syncthreads();

    const int c0 = t >> 4;
    const int s4 = t & 15;
    const f32x4 cv = *reinterpret_cast<const f32x4*>(&ctxl[s4 * 4]);
    const float* xb = x + (size_t)b * Cn * HWn + s0 + s4 * 4;
    float* ob = out + (size_t)b * Cn * HWn + s0 + s4 * 4;
    #pragma unroll
    for (int i = 0; i < 16; ++i) {
        const size_t off = (size_t)(c0 + 16 * i) * HWn;
        *reinterpret_cast<f32x4*>(ob + off) =
            *reinterpret_cast<const f32x4*>(xb + off) + cv;
    }
}

extern "C" void kernel_launch(void* const* d_in, const int* in_sizes, int n_in,
                              void* d_out, int out_size, void* d_ws, size_t ws_size,
                              hipStream_t stream)
{
    (void)in_sizes; (void)n_in; (void)out_size; (void)ws_size;
    const float* x     = (const float*)d_in[0];
    const float* w1    = (const float*)d_in[1];
    const float* b1    = (const float*)d_in[2];
    const float* gamma = (const float*)d_in[3];
    const float* beta  = (const float*)d_in[4];
    const float* mean  = (const float*)d_in[5];
    const float* var   = (const float*)d_in[6];
    const float* w2    = (const float*)d_in[7];
    const float* b2    = (const float*)d_in[8];
    const float* wm    = (const float*)d_in[9];
    // d_in[10] = bm: constant over softmax axis -> dropped

    float* out  = (float*)d_out;
    float* wsf  = (float*)d_ws;
    float* hmp  = wsf;                            // [4608*64] f32 tile partials
    float* wmix = hmp + NBLK1 * Pn;               // [64*64]
    float* bmix = wmix + Bn * HEADSn * Pn;        // [64]
    float* bcv  = bmix + 64;                      // [64]
    short* w1b  = (short*)(bcv + 64);             // [64*256] bf16, BN-scale folded
    short* hg   = w1b + Pn * Cn;                  // [16*9216*64] bf16

    k0_prep<<<dim3(8), dim3(256), 0, stream>>>(w1, b1, gamma, beta, mean, var, bcv, w1b);
    // DIAGNOSTIC: k1 and k3 at 2x grid (idempotent duplicate work) so their
    // dispatches exceed the ~85us ws-poison fills and surface in the top-5
    // rocprof rows with full counters (VGPR/Occupancy/VALUBusy/Mfma/LDS-conflict).
    k1_gemm<<<dim3(NBLK1 * DUP), dim3(128), 0, stream>>>(x, w1b, bcv, wm, hmp, hg);
    k2_mask<<<dim3(Bn * HEADSn), dim3(256), 0, stream>>>(hmp, w2, b2, wm, wmix, bmix);
    k3_stream<<<dim3(NTILE * DUP), dim3(256), 0, stream>>>(x, hg, wmix, bmix, out);
}

// Round 12
// 117.066 us; speedup vs baseline: 1.5779x; 1.5779x over previous
//
#include <hip/hip_runtime.h>

#define Bn 16
#define Cn 256
#define HWn 9216
#define Pn 64
#define HEADSn 4
#define Gn 2304
#define ST1 128                       // k1 spatial tile
#define T1_PER_B (HWn / ST1)          // 72
#define NBLK1 (Bn * T1_PER_B)         // 1152
#define TILES_PER_HEAD (Gn / ST1)     // 18

typedef float f32x4 __attribute__((ext_vector_type(4)));
typedef short short8 __attribute__((ext_vector_type(8)));
typedef unsigned int uint2v __attribute__((ext_vector_type(2)));
typedef unsigned int uint4v __attribute__((ext_vector_type(4)));

static __device__ __forceinline__ unsigned short f2bf(float f) {
    unsigned int b = __builtin_bit_cast(unsigned int, f);
    unsigned int r = b + 0x7FFFu + ((b >> 16) & 1u);   // RNE
    return (unsigned short)(r >> 16);
}
static __device__ __forceinline__ float bf2f(unsigned short u) {
    unsigned int b = ((unsigned int)u) << 16;
    return __builtin_bit_cast(float, b);
}
static __device__ __forceinline__ unsigned int cvtpk(float a, float b) {
    unsigned int r;
    asm("v_cvt_pk_bf16_f32 %0, %1, %2" : "=v"(r) : "v"(a), "v"(b));
    return r;
}
static __device__ __forceinline__ void gload_lds16(const void* g, void* l) {
    __builtin_amdgcn_global_load_lds((const __attribute__((address_space(1))) void*)g,
                                     (__attribute__((address_space(3))) void*)l, 16, 0, 0);
}

// ---- K0: w1 -> bf16 with BN scale folded per row; bc vector ----
__global__ __launch_bounds__(256)
void k0_prep(const float* __restrict__ w1, const float* __restrict__ b1,
             const float* __restrict__ gamma, const float* __restrict__ beta,
             const float* __restrict__ mean, const float* __restrict__ var,
             float* __restrict__ bcv, short* __restrict__ w1b)
{
    const int gid = blockIdx.x * 256 + threadIdx.x;
    if (gid < 2048) {
        const int row = gid >> 5;
        const float s = gamma[row] * rsqrtf(var[row] + 1e-5f);
        const float* p = w1 + gid * 8;
        short8 v;
        #pragma unroll
        for (int j = 0; j < 8; ++j) v[j] = (short)f2bf(p[j] * s);
        *reinterpret_cast<short8*>(&w1b[gid * 8]) = v;
    }
    if (gid < Pn) {
        const float s = gamma[gid] * rsqrtf(var[gid] + 1e-5f);
        bcv[gid] = (b1[gid] - mean[gid]) * s + beta[gid];
    }
}

// ---- K1: s-tile 128, 4 k-chunks of 64 c-rows via global_load_lds (512B/row reads) ----
// LDS chunk layout: word (k_loc, s_loc) = k_loc*128 + s_loc   (k_loc 0..63, s_loc 0..127)
__global__ __launch_bounds__(256, 8)
void k1_gemm(const float* __restrict__ x, const short* __restrict__ w1b,
             const float* __restrict__ bcv, const float* __restrict__ wm,
             float* __restrict__ hmp, short* __restrict__ hg)
{
    __shared__ float xl[64 * ST1];   // 32 KB f32 chunk
    __shared__ float hml[4][Pn];

    const int pid  = blockIdx.x;
    const int b    = pid / T1_PER_B;
    const int st   = pid % T1_PER_B;
    const int s0   = st * ST1;
    const int t    = threadIdx.x;
    const int lane = t & 63;
    const int wv   = t >> 6;
    const int wvu  = __builtin_amdgcn_readfirstlane(wv);
    const int g    = lane >> 4;
    const int m16  = lane & 15;
    const int scol0 = wv * 32 + m16;     // + cgi*16

    // ---- A-fragments (BN-scale folded), all 256 k, once: 128 VGPR ----
    short8 af[4][8];
    #pragma unroll
    for (int rt = 0; rt < 4; ++rt)
        #pragma unroll
        for (int kk = 0; kk < 8; ++kk)
            af[rt][kk] = *reinterpret_cast<const short8*>(
                w1b + (rt * 16 + m16) * Cn + kk * 32 + g * 8);

    float bc[4][4];
    #pragma unroll
    for (int rt = 0; rt < 4; ++rt)
        #pragma unroll
        for (int r = 0; r < 4; ++r) bc[rt][r] = bcv[rt * 16 + g * 4 + r];

    const float* xbb = x + (size_t)b * Cn * HWn + s0;
    f32x4 acc[2][4];
    #pragma unroll
    for (int cgi = 0; cgi < 2; ++cgi)
        #pragma unroll
        for (int rt = 0; rt < 4; ++rt) acc[cgi][rt] = f32x4{0.f, 0.f, 0.f, 0.f};

    #pragma unroll
    for (int kc = 0; kc < 4; ++kc) {
        // ---- stage 64 c-rows x 128 s, each instr = 2 rows x 512B contiguous ----
        #pragma unroll
        for (int i = 0; i < 8; ++i) {
            const int c = kc * 64 + wvu * 16 + i * 2 + (lane >> 5);
            gload_lds16(xbb + (size_t)c * HWn + (lane & 31) * 4,
                        &xl[(wvu * 8 + i) * 256]);
        }
        __syncthreads();

        // ---- MFMA: 2 K32 steps x 2 col-groups x 4 row-tiles ----
        #pragma unroll
        for (int ks2 = 0; ks2 < 2; ++ks2) {
            #pragma unroll
            for (int cgi = 0; cgi < 2; ++cgi) {
                const int sc = scol0 + cgi * 16;
                uint4v bu;
                #pragma unroll
                for (int jp = 0; jp < 4; ++jp) {
                    const int kl = ks2 * 32 + g * 8 + jp * 2;
                    bu[jp] = cvtpk(xl[kl * ST1 + sc], xl[(kl + 1) * ST1 + sc]);
                }
                const short8 bf = __builtin_bit_cast(short8, bu);
                #pragma unroll
                for (int rt = 0; rt < 4; ++rt)
                    acc[cgi][rt] = __builtin_amdgcn_mfma_f32_16x16x32_bf16(
                        af[rt][kc * 2 + ks2], bf, acc[cgi][rt], 0, 0, 0);
            }
        }
        __syncthreads();
    }

    // ---- bias + ReLU + h store [s][p] + hm register accumulate ----
    float hmacc[4][4];
    #pragma unroll
    for (int rt = 0; rt < 4; ++rt)
        #pragma unroll
        for (int r = 0; r < 4; ++r) hmacc[rt][r] = 0.f;

    #pragma unroll
    for (int cgi = 0; cgi < 2; ++cgi) {
        const int sg = s0 + wv * 32 + cgi * 16 + m16;
        const float wmv = wm[sg];
        short* hrow = hg + ((size_t)b * HWn + sg) * Pn;
        #pragma unroll
        for (int rt = 0; rt < 4; ++rt) {
            float h[4];
            #pragma unroll
            for (int r = 0; r < 4; ++r) {
                float hv = acc[cgi][rt][r] + bc[rt][r];
                hv = hv > 0.f ? hv : 0.f;
                hmacc[rt][r] = fmaf(hv, wmv, hmacc[rt][r]);
                h[r] = hv;
            }
            uint2v pk;
            pk[0] = cvtpk(h[0], h[1]);
            pk[1] = cvtpk(h[2], h[3]);
            *reinterpret_cast<uint2v*>(hrow + rt * 16 + g * 4) = pk;
        }
    }

    // ---- hm partial: shfl over 16 s-cols, 4-wave LDS combine, one store ----
    #pragma unroll
    for (int rt = 0; rt < 4; ++rt)
        #pragma unroll
        for (int r = 0; r < 4; ++r) {
            float v = hmacc[rt][r];
            v += __shfl_xor(v, 1); v += __shfl_xor(v, 2);
            v += __shfl_xor(v, 4); v += __shfl_xor(v, 8);
            hmacc[rt][r] = v;
        }
    if (m16 == 0) {
        #pragma unroll
        for (int rt = 0; rt < 4; ++rt) {
            f32x4 hv = { hmacc[rt][0], hmacc[rt][1], hmacc[rt][2], hmacc[rt][3] };
            *reinterpret_cast<f32x4*>(&hml[wv][rt * 16 + g * 4]) = hv;
        }
    }
    __syncthreads();
    if (t < Pn) hmp[pid * Pn + t] = hml[0][t] + hml[1][t] + hml[2][t] + hml[3][t];
}

// ---- K2: reduce 18 tile-partials -> logits -> softmax -> wmix/bmix ----
__global__ __launch_bounds__(256)
void k2_mask(const float* __restrict__ hmp, const float* __restrict__ w2,
             const float* __restrict__ b2, const float* __restrict__ wm,
             float* __restrict__ wmix, float* __restrict__ bmix)
{
    __shared__ float hms[Pn];
    __shared__ float masks[Cn];
    __shared__ float red[4];
    __shared__ float part[4][Pn];

    const int bh = blockIdx.x;
    const int head = bh & (HEADSn - 1);
    const int t = threadIdx.x;
    const int l = t & 63;
    const int wv = t >> 6;

    // this (b,head)'s 18 partials: blocks (b*72 + head*18) .. +17
    {
        const int p = t & 63, q = t >> 6;
        const float* base = hmp + ((size_t)(bh >> 2) * T1_PER_B + head * TILES_PER_HEAD) * Pn;
        float sp = 0.f;
        #pragma unroll
        for (int j = 0; j < 5; ++j) {
            const int idx = q + 4 * j;
            if (idx < TILES_PER_HEAD) sp += base[idx * Pn + p];
        }
        part[q][p] = sp;
    }
    __syncthreads();
    if (t < Pn) hms[t] = part[0][t] + part[1][t] + part[2][t] + part[3][t];
    __syncthreads();

    // wmsum over this head's group
    float wsum = 0.f;
    for (int i = t; i < Gn; i += 256) wsum += wm[head * Gn + i];
    #pragma unroll
    for (int d = 1; d < 64; d <<= 1) wsum += __shfl_xor(wsum, d);
    if (l == 0) red[wv] = wsum;
    __syncthreads();
    wsum = red[0] + red[1] + red[2] + red[3];

    // logits[c] = sum_k w2[c,k]*hm[k] + b2[c]*wsum
    float lg = 0.f;
    #pragma unroll
    for (int k = 0; k < Pn; ++k) lg = fmaf(w2[t * Pn + k], hms[k], lg);
    lg = fmaf(b2[t], wsum, lg);

    // softmax over 256 channels
    float mx = lg;
    #pragma unroll
    for (int d = 1; d < 64; d <<= 1) mx = fmaxf(mx, __shfl_xor(mx, d));
    __syncthreads();
    if (l == 0) red[wv] = mx;
    __syncthreads();
    mx = fmaxf(fmaxf(red[0], red[1]), fmaxf(red[2], red[3]));
    const float ev = __expf(lg - mx);
    float sm = ev;
    #pragma unroll
    for (int d = 1; d < 64; d <<= 1) sm += __shfl_xor(sm, d);
    __syncthreads();
    if (l == 0) red[wv] = sm;
    __syncthreads();
    sm = red[0] + red[1] + red[2] + red[3];
    masks[t] = ev / sm;
    __syncthreads();

    // wmix[k] = sum_c mask[c]*w2[c,k]
    {
        const int k = t & (Pn - 1);
        const int q = t >> 6;
        float wp = 0.f;
        #pragma unroll
        for (int i = 0; i < 64; ++i) {
            const int c = q * 64 + i;
            wp = fmaf(masks[c], w2[c * Pn + k], wp);
        }
        part[q][k] = wp;
    }
    __syncthreads();
    if (t < Pn) wmix[bh * Pn + t] = part[0][t] + part[1][t] + part[2][t] + part[3][t];

    // bmix = sum_c mask[c]*b2[c]
    float bp = masks[t] * b2[t];
    #pragma unroll
    for (int d = 1; d < 64; d <<= 1) bp += __shfl_xor(bp, d);
    __syncthreads();
    if (l == 0) red[wv] = bp;
    __syncthreads();
    if (t == 0) bmix[bh] = red[0] + red[1] + red[2] + red[3];
}

// ---- K2b: ctx[b][s] = wmix . h[s,:] + bmix  (coalesced h rows, 8 lanes/row) ----
__global__ __launch_bounds__(256)
void k2b_ctx(const short* __restrict__ hg, const float* __restrict__ wmix,
             const float* __restrict__ bmix, float* __restrict__ ctxb)
{
    const int bid = blockIdx.x;
    const int b   = bid / 288;
    const int s32 = bid % 288;             // 32 s-rows per block
    const int head = s32 / 72;             // uniform per block
    const int bh  = b * HEADSn + head;
    const int t   = threadIdx.x;
    const int sr  = t >> 3;
    const int j8  = t & 7;
    const int s   = s32 * 32 + sr;

    const short8 hv = *reinterpret_cast<const short8*>(
        hg + ((size_t)b * HWn + s) * Pn + j8 * 8);
    const f32x4 w0 = *reinterpret_cast<const f32x4*>(wmix + bh * Pn + j8 * 8);
    const f32x4 w1v = *reinterpret_cast<const f32x4*>(wmix + bh * Pn + j8 * 8 + 4);
    float acc = 0.f;
    #pragma unroll
    for (int j = 0; j < 4; ++j) {
        acc = fmaf(bf2f((unsigned short)hv[j]), w0[j], acc);
        acc = fmaf(bf2f((unsigned short)hv[4 + j]), w1v[j], acc);
    }
    acc += __shfl_xor(acc, 1);
    acc += __shfl_xor(acc, 2);
    acc += __shfl_xor(acc, 4);
    if (j8 == 0) ctxb[(size_t)b * HWn + s] = acc + bmix[bh];
}

// ---- K3: fully contiguous: block owns 4 whole c-rows; ctx cached in registers ----
__global__ __launch_bounds__(256)
void k3_stream(const float* __restrict__ x, const float* __restrict__ ctxb,
               float* __restrict__ out)
{
    const int bid = blockIdx.x;
    const int b   = bid >> 6;
    const int c0  = (bid & 63) * 4;
    const int t   = threadIdx.x;

    f32x4 cv[9];
    #pragma unroll
    for (int j = 0; j < 9; ++j)
        cv[j] = *reinterpret_cast<const f32x4*>(ctxb + (size_t)b * HWn + (j * 256 + t) * 4);

    #pragma unroll
    for (int ci = 0; ci < 4; ++ci) {
        const float* xr = x + ((size_t)b * Cn + c0 + ci) * HWn;
        float* orow = out + ((size_t)b * Cn + c0 + ci) * HWn;
        #pragma unroll
        for (int j = 0; j < 9; ++j) {
            const int off = (j * 256 + t) * 4;
            *reinterpret_cast<f32x4*>(orow + off) =
                *reinterpret_cast<const f32x4*>(xr + off) + cv[j];
        }
    }
}

extern "C" void kernel_launch(void* const* d_in, const int* in_sizes, int n_in,
                              void* d_out, int out_size, void* d_ws, size_t ws_size,
                              hipStream_t stream)
{
    (void)in_sizes; (void)n_in; (void)out_size; (void)ws_size;
    const float* x     = (const float*)d_in[0];
    const float* w1    = (const float*)d_in[1];
    const float* b1    = (const float*)d_in[2];
    const float* gamma = (const float*)d_in[3];
    const float* beta  = (const float*)d_in[4];
    const float* mean  = (const float*)d_in[5];
    const float* var   = (const float*)d_in[6];
    const float* w2    = (const float*)d_in[7];
    const float* b2    = (const float*)d_in[8];
    const float* wm    = (const float*)d_in[9];
    // d_in[10] = bm: constant over softmax axis -> dropped

    float* out  = (float*)d_out;
    float* wsf  = (float*)d_ws;
    float* hmp  = wsf;                            // [1152*64]
    float* wmix = hmp + NBLK1 * Pn;               // [64*64]
    float* bmix = wmix + Bn * HEADSn * Pn;        // [64]
    float* bcv  = bmix + 64;                      // [64]
    float* ctxb = bcv + 64;                       // [16*9216] f32
    short* w1b  = (short*)(ctxb + Bn * HWn);      // [64*256] bf16 scale-folded
    short* hg   = w1b + Pn * Cn;                  // [16*9216*64] bf16

    k0_prep<<<dim3(8), dim3(256), 0, stream>>>(w1, b1, gamma, beta, mean, var, bcv, w1b);
    k1_gemm<<<dim3(NBLK1), dim3(256), 0, stream>>>(x, w1b, bcv, wm, hmp, hg);
    k2_mask<<<dim3(Bn * HEADSn), dim3(256), 0, stream>>>(hmp, w2, b2, wm, wmix, bmix);
    k2b_ctx<<<dim3(Bn * 288), dim3(256), 0, stream>>>(hg, wmix, bmix, ctxb);
    k3_stream<<<dim3(Bn * 64), dim3(256), 0, stream>>>(x, ctxb, out);
}

// Round 13
// 107.877 us; speedup vs baseline: 1.7123x; 1.0852x over previous
//
#include <hip/hip_runtime.h>

#define Bn 16
#define Cn 256
#define HWn 9216
#define Pn 64
#define HEADSn 4
#define Gn 2304
#define T32_PER_B 288                // 32-col tiles per batch (k1)
#define NBLK1 (Bn * T32_PER_B)       // 4608 k1 blocks

typedef float f32x4 __attribute__((ext_vector_type(4)));
typedef short short8 __attribute__((ext_vector_type(8)));
typedef unsigned int uint2v __attribute__((ext_vector_type(2)));

static __device__ __forceinline__ unsigned short f2bf(float f) {
    unsigned int b = __builtin_bit_cast(unsigned int, f);
    unsigned int r = b + 0x7FFFu + ((b >> 16) & 1u);   // RNE
    return (unsigned short)(r >> 16);
}
static __device__ __forceinline__ float bf2f(unsigned short u) {
    unsigned int b = ((unsigned int)u) << 16;
    return __builtin_bit_cast(float, b);
}
static __device__ __forceinline__ unsigned int cvtpk(float a, float b) {
    unsigned int r;
    asm("v_cvt_pk_bf16_f32 %0, %1, %2" : "=v"(r) : "v"(a), "v"(b));
    return r;
}

// ---- K0: w1 -> bf16 with BN scale folded per row; bc vector ----
__global__ __launch_bounds__(256)
void k0_prep(const float* __restrict__ w1, const float* __restrict__ b1,
             const float* __restrict__ gamma, const float* __restrict__ beta,
             const float* __restrict__ mean, const float* __restrict__ var,
             float* __restrict__ bcv, short* __restrict__ w1b)
{
    const int gid = blockIdx.x * 256 + threadIdx.x;
    if (gid < 2048) {
        const int row = gid >> 5;
        const float s = gamma[row] * rsqrtf(var[row] + 1e-5f);
        const float* p = w1 + gid * 8;
        short8 v;
        #pragma unroll
        for (int j = 0; j < 8; ++j) v[j] = (short)f2bf(p[j] * s);
        *reinterpret_cast<short8*>(&w1b[gid * 8]) = v;
    }
    if (gid < Pn) {
        const float s = gamma[gid] * rsqrtf(var[gid] + 1e-5f);
        bcv[gid] = (b1[gid] - mean[gid]) * s + beta[gid];
    }
}

// ---- K1 (round-10 kernel, k1 ~= 36.5us): 128 thr, 32-col tiles, 16KB LDS ----
// LDS swizzle: elem (k, s in 0..31) -> byte k*64 + (((s>>3) ^ f(k))*16) + (s&7)*2,
// f(k) = (k ^ (k>>2)) & 3;  bf16 conversion on the WRITE path (cvt_pk).
__global__ __launch_bounds__(128, 4)
void k1_gemm(const float* __restrict__ x, const short* __restrict__ w1b,
             const float* __restrict__ bcv, const float* __restrict__ wm,
             float* __restrict__ hmp, short* __restrict__ hg)
{
    __shared__ short xl[Cn * 32];          // 16 KB bf16, swizzled

    const int bid  = blockIdx.x;
    const int b    = bid / T32_PER_B;
    const int t32  = bid % T32_PER_B;
    const int s0   = t32 * 32;
    const int t    = threadIdx.x;
    const int lane = t & 63;
    const int wv   = t >> 6;               // 0..1, owns p in [wv*32, wv*32+32)
    const int g    = lane >> 4;
    const int m16  = lane & 15;

    // ---- A-fragments (BN-scale folded) into registers: 64 VGPR ----
    short8 af[2][8];
    #pragma unroll
    for (int rt = 0; rt < 2; ++rt)
        #pragma unroll
        for (int ks = 0; ks < 8; ++ks)
            af[rt][ks] = *reinterpret_cast<const short8*>(
                w1b + (wv * 32 + rt * 16 + m16) * Cn + ks * 32 + g * 8);

    float bc[2][4];
    #pragma unroll
    for (int rt = 0; rt < 2; ++rt)
        #pragma unroll
        for (int r = 0; r < 4; ++r) bc[rt][r] = bcv[wv * 32 + rt * 16 + g * 4 + r];

    // ---- stage x tile: thread (krow=t>>3, chk=t&7); coalesced 128B per 8 lanes ----
    const int krow = t >> 3;
    const int chk  = t & 7;
    const float* xb = x + (size_t)b * Cn * HWn + s0 + chk * 4;
    #pragma unroll
    for (int i = 0; i < 16; ++i) {
        const int k = i * 16 + krow;
        const f32x4 v = *reinterpret_cast<const f32x4*>(xb + (size_t)k * HWn);
        uint2v pk;
        pk[0] = cvtpk(v[0], v[1]);
        pk[1] = cvtpk(v[2], v[3]);
        const int f    = (k ^ (k >> 2)) & 3;
        const int byte = k * 64 + (((chk >> 1) ^ f) * 16) + (chk & 1) * 8;
        *reinterpret_cast<uint2v*>(reinterpret_cast<char*>(xl) + byte) = pk;
    }
    __syncthreads();

    // ---- GEMM1: 8 ks x { 2 cg x (8 bf16 reads + 2 MFMA) } ----
    f32x4 acc[2][2] = { { {0,0,0,0}, {0,0,0,0} }, { {0,0,0,0}, {0,0,0,0} } };
    #pragma unroll
    for (int ks = 0; ks < 8; ++ks) {
        #pragma unroll
        for (int cg = 0; cg < 2; ++cg) {
            short8 bf;
            #pragma unroll
            for (int j = 0; j < 8; ++j) {
                const int k    = ks * 32 + g * 8 + j;
                const int f    = (k ^ (k >> 2)) & 3;
                const int byte = k * 64 + ((((cg * 2) + (m16 >> 3)) ^ f) * 16) + (m16 & 7) * 2;
                bf[j] = *reinterpret_cast<const short*>(
                    reinterpret_cast<const char*>(xl) + byte);
            }
            acc[cg][0] = __builtin_amdgcn_mfma_f32_16x16x32_bf16(af[0][ks], bf, acc[cg][0], 0, 0, 0);
            acc[cg][1] = __builtin_amdgcn_mfma_f32_16x16x32_bf16(af[1][ks], bf, acc[cg][1], 0, 0, 0);
        }
    }

    // ---- bias + ReLU + h store [s][p] + hm register accumulate ----
    const float wmv0 = wm[s0 + m16];
    const float wmv1 = wm[s0 + 16 + m16];
    float hmacc[2][4];
    #pragma unroll
    for (int rt = 0; rt < 2; ++rt)
        #pragma unroll
        for (int r = 0; r < 4; ++r) hmacc[rt][r] = 0.f;

    #pragma unroll
    for (int cg = 0; cg < 2; ++cg) {
        const float wmv = cg ? wmv1 : wmv0;
        short* hrow = hg + ((size_t)b * HWn + s0 + cg * 16 + m16) * Pn + wv * 32;
        #pragma unroll
        for (int rt = 0; rt < 2; ++rt) {
            float h[4];
            #pragma unroll
            for (int r = 0; r < 4; ++r) {
                float hv = acc[cg][rt][r] + bc[rt][r];
                hv = hv > 0.f ? hv : 0.f;
                hmacc[rt][r] = fmaf(hv, wmv, hmacc[rt][r]);
                h[r] = hv;
            }
            uint2v pk;
            pk[0] = cvtpk(h[0], h[1]);
            pk[1] = cvtpk(h[2], h[3]);
            *reinterpret_cast<uint2v*>(hrow + rt * 16 + g * 4) = pk;
        }
    }

    // ---- hm partial: reduce over the 16 s-columns (shfl), store per-block ----
    #pragma unroll
    for (int rt = 0; rt < 2; ++rt)
        #pragma unroll
        for (int r = 0; r < 4; ++r) {
            float v = hmacc[rt][r];
            v += __shfl_xor(v, 1); v += __shfl_xor(v, 2);
            v += __shfl_xor(v, 4); v += __shfl_xor(v, 8);
            hmacc[rt][r] = v;
        }
    if (m16 == 0) {
        #pragma unroll
        for (int rt = 0; rt < 2; ++rt)
            #pragma unroll
            for (int r = 0; r < 4; ++r)
                hmp[bid * Pn + wv * 32 + rt * 16 + g * 4 + r] = hmacc[rt][r];
    }
}

// ---- K2: reduce 72 tile-partials -> logits -> softmax -> wmix/bmix ----
__global__ __launch_bounds__(256)
void k2_mask(const float* __restrict__ hmp, const float* __restrict__ w2,
             const float* __restrict__ b2, const float* __restrict__ wm,
             float* __restrict__ wmix, float* __restrict__ bmix)
{
    __shared__ float hms[Pn];
    __shared__ float masks[Cn];
    __shared__ float red[4];
    __shared__ float part[4][Pn];

    const int bh = blockIdx.x;
    const int head = bh & (HEADSn - 1);
    const int t = threadIdx.x;
    const int l = t & 63;
    const int wv = t >> 6;

    // this (b,head)'s partials: blocks (b*288 + head*72) .. +71
    {
        const int p = t & 63, q = t >> 6;
        const float* base = hmp + ((size_t)(bh >> 2) * T32_PER_B + head * 72) * Pn;
        float sp = 0.f;
        #pragma unroll
        for (int jj = 0; jj < 18; ++jj) sp += base[(q + 4 * jj) * Pn + p];
        part[q][p] = sp;
    }
    __syncthreads();
    if (t < Pn) hms[t] = part[0][t] + part[1][t] + part[2][t] + part[3][t];
    __syncthreads();

    // wmsum over this head's group
    float wsum = 0.f;
    for (int i = t; i < Gn; i += 256) wsum += wm[head * Gn + i];
    #pragma unroll
    for (int d = 1; d < 64; d <<= 1) wsum += __shfl_xor(wsum, d);
    if (l == 0) red[wv] = wsum;
    __syncthreads();
    wsum = red[0] + red[1] + red[2] + red[3];

    // logits[c] = sum_k w2[c,k]*hm[k] + b2[c]*wsum
    float lg = 0.f;
    #pragma unroll
    for (int k = 0; k < Pn; ++k) lg = fmaf(w2[t * Pn + k], hms[k], lg);
    lg = fmaf(b2[t], wsum, lg);

    // softmax over 256 channels
    float mx = lg;
    #pragma unroll
    for (int d = 1; d < 64; d <<= 1) mx = fmaxf(mx, __shfl_xor(mx, d));
    __syncthreads();
    if (l == 0) red[wv] = mx;
    __syncthreads();
    mx = fmaxf(fmaxf(red[0], red[1]), fmaxf(red[2], red[3]));
    const float ev = __expf(lg - mx);
    float sm = ev;
    #pragma unroll
    for (int d = 1; d < 64; d <<= 1) sm += __shfl_xor(sm, d);
    __syncthreads();
    if (l == 0) red[wv] = sm;
    __syncthreads();
    sm = red[0] + red[1] + red[2] + red[3];
    masks[t] = ev / sm;
    __syncthreads();

    // wmix[k] = sum_c mask[c]*w2[c,k]
    {
        const int k = t & (Pn - 1);
        const int q = t >> 6;
        float wp = 0.f;
        #pragma unroll
        for (int i = 0; i < 64; ++i) {
            const int c = q * 64 + i;
            wp = fmaf(masks[c], w2[c * Pn + k], wp);
        }
        part[q][k] = wp;
    }
    __syncthreads();
    if (t < Pn) wmix[bh * Pn + t] = part[0][t] + part[1][t] + part[2][t] + part[3][t];

    // bmix = sum_c mask[c]*b2[c]
    float bp = masks[t] * b2[t];
    #pragma unroll
    for (int d = 1; d < 64; d <<= 1) bp += __shfl_xor(bp, d);
    __syncthreads();
    if (l == 0) red[wv] = bp;
    __syncthreads();
    if (t == 0) bmix[bh] = red[0] + red[1] + red[2] + red[3];
}

// ---- K2b: ctx[b][s] = wmix . h[s,:] + bmix  (coalesced h rows, 8 lanes/row) ----
__global__ __launch_bounds__(256)
void k2b_ctx(const short* __restrict__ hg, const float* __restrict__ wmix,
             const float* __restrict__ bmix, float* __restrict__ ctxb)
{
    const int bid = blockIdx.x;
    const int b   = bid / 288;
    const int s32 = bid % 288;             // 32 s-rows per block
    const int head = s32 / 72;             // uniform per block
    const int bh  = b * HEADSn + head;
    const int t   = threadIdx.x;
    const int sr  = t >> 3;
    const int j8  = t & 7;
    const int s   = s32 * 32 + sr;

    const short8 hv = *reinterpret_cast<const short8*>(
        hg + ((size_t)b * HWn + s) * Pn + j8 * 8);
    const f32x4 w0 = *reinterpret_cast<const f32x4*>(wmix + bh * Pn + j8 * 8);
    const f32x4 w1v = *reinterpret_cast<const f32x4*>(wmix + bh * Pn + j8 * 8 + 4);
    float acc = 0.f;
    #pragma unroll
    for (int j = 0; j < 4; ++j) {
        acc = fmaf(bf2f((unsigned short)hv[j]), w0[j], acc);
        acc = fmaf(bf2f((unsigned short)hv[4 + j]), w1v[j], acc);
    }
    acc += __shfl_xor(acc, 1);
    acc += __shfl_xor(acc, 2);
    acc += __shfl_xor(acc, 4);
    if (j8 == 0) ctxb[(size_t)b * HWn + s] = acc + bmix[bh];
}

// ---- K3: fully contiguous: block owns 4 whole c-rows; ctx cached in registers ----
__global__ __launch_bounds__(256)
void k3_stream(const float* __restrict__ x, const float* __restrict__ ctxb,
               float* __restrict__ out)
{
    const int bid = blockIdx.x;
    const int b   = bid >> 6;
    const int c0  = (bid & 63) * 4;
    const int t   = threadIdx.x;

    f32x4 cv[9];
    #pragma unroll
    for (int j = 0; j < 9; ++j)
        cv[j] = *reinterpret_cast<const f32x4*>(ctxb + (size_t)b * HWn + (j * 256 + t) * 4);

    #pragma unroll
    for (int ci = 0; ci < 4; ++ci) {
        const float* xr = x + ((size_t)b * Cn + c0 + ci) * HWn;
        float* orow = out + ((size_t)b * Cn + c0 + ci) * HWn;
        #pragma unroll
        for (int j = 0; j < 9; ++j) {
            const int off = (j * 256 + t) * 4;
            *reinterpret_cast<f32x4*>(orow + off) =
                *reinterpret_cast<const f32x4*>(xr + off) + cv[j];
        }
    }
}

extern "C" void kernel_launch(void* const* d_in, const int* in_sizes, int n_in,
                              void* d_out, int out_size, void* d_ws, size_t ws_size,
                              hipStream_t stream)
{
    (void)in_sizes; (void)n_in; (void)out_size; (void)ws_size;
    const float* x     = (const float*)d_in[0];
    const float* w1    = (const float*)d_in[1];
    const float* b1    = (const float*)d_in[2];
    const float* gamma = (const float*)d_in[3];
    const float* beta  = (const float*)d_in[4];
    const float* mean  = (const float*)d_in[5];
    const float* var   = (const float*)d_in[6];
    const float* w2    = (const float*)d_in[7];
    const float* b2    = (const float*)d_in[8];
    const float* wm    = (const float*)d_in[9];
    // d_in[10] = bm: constant over softmax axis -> dropped

    float* out  = (float*)d_out;
    float* wsf  = (float*)d_ws;
    float* hmp  = wsf;                            // [4608*64] f32 tile partials
    float* wmix = hmp + NBLK1 * Pn;               // [64*64]
    float* bmix = wmix + Bn * HEADSn * Pn;        // [64]
    float* bcv  = bmix + 64;                      // [64]
    float* ctxb = bcv + 64;                       // [16*9216] f32
    short* w1b  = (short*)(ctxb + Bn * HWn);      // [64*256] bf16 scale-folded
    short* hg   = w1b + Pn * Cn;                  // [16*9216*64] bf16

    k0_prep<<<dim3(8), dim3(256), 0, stream>>>(w1, b1, gamma, beta, mean, var, bcv, w1b);
    k1_gemm<<<dim3(NBLK1), dim3(128), 0, stream>>>(x, w1b, bcv, wm, hmp, hg);
    k2_mask<<<dim3(Bn * HEADSn), dim3(256), 0, stream>>>(hmp, w2, b2, wm, wmix, bmix);
    k2b_ctx<<<dim3(Bn * 288), dim3(256), 0, stream>>>(hg, wmix, bmix, ctxb);
    k3_stream<<<dim3(Bn * 64), dim3(256), 0, stream>>>(x, ctxb, out);
}

// Round 14
// 102.475 us; speedup vs baseline: 1.8025x; 1.0527x over previous
//
#include <hip/hip_runtime.h>

#define Bn 16
#define Cn 256
#define HWn 9216
#define Pn 64
#define HEADSn 4
#define Gn 2304
#define T32_PER_B 288                // 32-col tiles per batch (k1)
#define NBLK1 (Bn * T32_PER_B)       // 4608 k1 blocks
#define ST3 128                      // k3 spatial tile
#define T3_PER_B (HWn / ST3)         // 72
#define NBLK3 (Bn * T3_PER_B)        // 1152 k3 blocks

typedef float f32x4 __attribute__((ext_vector_type(4)));
typedef short short8 __attribute__((ext_vector_type(8)));
typedef unsigned int uint2v __attribute__((ext_vector_type(2)));

static __device__ __forceinline__ unsigned short f2bf(float f) {
    unsigned int b = __builtin_bit_cast(unsigned int, f);
    unsigned int r = b + 0x7FFFu + ((b >> 16) & 1u);   // RNE
    return (unsigned short)(r >> 16);
}
static __device__ __forceinline__ float bf2f(unsigned short u) {
    unsigned int b = ((unsigned int)u) << 16;
    return __builtin_bit_cast(float, b);
}
static __device__ __forceinline__ unsigned int cvtpk(float a, float b) {
    unsigned int r;
    asm("v_cvt_pk_bf16_f32 %0, %1, %2" : "=v"(r) : "v"(a), "v"(b));
    return r;
}

// ---- K0: w1 -> bf16 with BN scale folded per row; bc vector ----
__global__ __launch_bounds__(256)
void k0_prep(const float* __restrict__ w1, const float* __restrict__ b1,
             const float* __restrict__ gamma, const float* __restrict__ beta,
             const float* __restrict__ mean, const float* __restrict__ var,
             float* __restrict__ bcv, short* __restrict__ w1b)
{
    const int gid = blockIdx.x * 256 + threadIdx.x;
    if (gid < 2048) {
        const int row = gid >> 5;
        const float s = gamma[row] * rsqrtf(var[row] + 1e-5f);
        const float* p = w1 + gid * 8;
        short8 v;
        #pragma unroll
        for (int j = 0; j < 8; ++j) v[j] = (short)f2bf(p[j] * s);
        *reinterpret_cast<short8*>(&w1b[gid * 8]) = v;
    }
    if (gid < Pn) {
        const float s = gamma[gid] * rsqrtf(var[gid] + 1e-5f);
        bcv[gid] = (b1[gid] - mean[gid]) * s + beta[gid];
    }
}

// ---- K1 (round-10 kernel, measured ~36.5us): 128 thr, 32-col tiles, 16KB LDS ----
// LDS swizzle: elem (k, s in 0..31) -> byte k*64 + (((s>>3) ^ f(k))*16) + (s&7)*2,
// f(k) = (k ^ (k>>2)) & 3;  bf16 conversion on the WRITE path (cvt_pk).
__global__ __launch_bounds__(128, 4)
void k1_gemm(const float* __restrict__ x, const short* __restrict__ w1b,
             const float* __restrict__ bcv, const float* __restrict__ wm,
             float* __restrict__ hmp, short* __restrict__ hg)
{
    __shared__ short xl[Cn * 32];          // 16 KB bf16, swizzled

    const int bid  = blockIdx.x;
    const int b    = bid / T32_PER_B;
    const int t32  = bid % T32_PER_B;
    const int s0   = t32 * 32;
    const int t    = threadIdx.x;
    const int lane = t & 63;
    const int wv   = t >> 6;               // 0..1, owns p in [wv*32, wv*32+32)
    const int g    = lane >> 4;
    const int m16  = lane & 15;

    // ---- A-fragments (BN-scale folded) into registers: 64 VGPR ----
    short8 af[2][8];
    #pragma unroll
    for (int rt = 0; rt < 2; ++rt)
        #pragma unroll
        for (int ks = 0; ks < 8; ++ks)
            af[rt][ks] = *reinterpret_cast<const short8*>(
                w1b + (wv * 32 + rt * 16 + m16) * Cn + ks * 32 + g * 8);

    float bc[2][4];
    #pragma unroll
    for (int rt = 0; rt < 2; ++rt)
        #pragma unroll
        for (int r = 0; r < 4; ++r) bc[rt][r] = bcv[wv * 32 + rt * 16 + g * 4 + r];

    // ---- stage x tile: thread (krow=t>>3, chk=t&7); coalesced 128B per 8 lanes ----
    const int krow = t >> 3;
    const int chk  = t & 7;
    const float* xb = x + (size_t)b * Cn * HWn + s0 + chk * 4;
    #pragma unroll
    for (int i = 0; i < 16; ++i) {
        const int k = i * 16 + krow;
        const f32x4 v = *reinterpret_cast<const f32x4*>(xb + (size_t)k * HWn);
        uint2v pk;
        pk[0] = cvtpk(v[0], v[1]);
        pk[1] = cvtpk(v[2], v[3]);
        const int f    = (k ^ (k >> 2)) & 3;
        const int byte = k * 64 + (((chk >> 1) ^ f) * 16) + (chk & 1) * 8;
        *reinterpret_cast<uint2v*>(reinterpret_cast<char*>(xl) + byte) = pk;
    }
    __syncthreads();

    // ---- GEMM1: 8 ks x { 2 cg x (8 bf16 reads + 2 MFMA) } ----
    f32x4 acc[2][2] = { { {0,0,0,0}, {0,0,0,0} }, { {0,0,0,0}, {0,0,0,0} } };
    #pragma unroll
    for (int ks = 0; ks < 8; ++ks) {
        #pragma unroll
        for (int cg = 0; cg < 2; ++cg) {
            short8 bf;
            #pragma unroll
            for (int j = 0; j < 8; ++j) {
                const int k    = ks * 32 + g * 8 + j;
                const int f    = (k ^ (k >> 2)) & 3;
                const int byte = k * 64 + ((((cg * 2) + (m16 >> 3)) ^ f) * 16) + (m16 & 7) * 2;
                bf[j] = *reinterpret_cast<const short*>(
                    reinterpret_cast<const char*>(xl) + byte);
            }
            acc[cg][0] = __builtin_amdgcn_mfma_f32_16x16x32_bf16(af[0][ks], bf, acc[cg][0], 0, 0, 0);
            acc[cg][1] = __builtin_amdgcn_mfma_f32_16x16x32_bf16(af[1][ks], bf, acc[cg][1], 0, 0, 0);
        }
    }

    // ---- bias + ReLU + h store [s][p] + hm register accumulate ----
    const float wmv0 = wm[s0 + m16];
    const float wmv1 = wm[s0 + 16 + m16];
    float hmacc[2][4];
    #pragma unroll
    for (int rt = 0; rt < 2; ++rt)
        #pragma unroll
        for (int r = 0; r < 4; ++r) hmacc[rt][r] = 0.f;

    #pragma unroll
    for (int cg = 0; cg < 2; ++cg) {
        const float wmv = cg ? wmv1 : wmv0;
        short* hrow = hg + ((size_t)b * HWn + s0 + cg * 16 + m16) * Pn + wv * 32;
        #pragma unroll
        for (int rt = 0; rt < 2; ++rt) {
            float h[4];
            #pragma unroll
            for (int r = 0; r < 4; ++r) {
                float hv = acc[cg][rt][r] + bc[rt][r];
                hv = hv > 0.f ? hv : 0.f;
                hmacc[rt][r] = fmaf(hv, wmv, hmacc[rt][r]);
                h[r] = hv;
            }
            uint2v pk;
            pk[0] = cvtpk(h[0], h[1]);
            pk[1] = cvtpk(h[2], h[3]);
            *reinterpret_cast<uint2v*>(hrow + rt * 16 + g * 4) = pk;
        }
    }

    // ---- hm partial: reduce over the 16 s-columns (shfl), store per-block ----
    #pragma unroll
    for (int rt = 0; rt < 2; ++rt)
        #pragma unroll
        for (int r = 0; r < 4; ++r) {
            float v = hmacc[rt][r];
            v += __shfl_xor(v, 1); v += __shfl_xor(v, 2);
            v += __shfl_xor(v, 4); v += __shfl_xor(v, 8);
            hmacc[rt][r] = v;
        }
    if (m16 == 0) {
        #pragma unroll
        for (int rt = 0; rt < 2; ++rt)
            #pragma unroll
            for (int r = 0; r < 4; ++r)
                hmp[bid * Pn + wv * 32 + rt * 16 + g * 4 + r] = hmacc[rt][r];
    }
}

// ---- K2: reduce 72 tile-partials -> logits -> softmax -> wmix/bmix ----
__global__ __launch_bounds__(256)
void k2_mask(const float* __restrict__ hmp, const float* __restrict__ w2,
             const float* __restrict__ b2, const float* __restrict__ wm,
             float* __restrict__ wmix, float* __restrict__ bmix)
{
    __shared__ float hms[Pn];
    __shared__ float masks[Cn];
    __shared__ float red[4];
    __shared__ float part[4][Pn];

    const int bh = blockIdx.x;
    const int head = bh & (HEADSn - 1);
    const int t = threadIdx.x;
    const int l = t & 63;
    const int wv = t >> 6;

    // this (b,head)'s partials: blocks (b*288 + head*72) .. +71
    {
        const int p = t & 63, q = t >> 6;
        const float* base = hmp + ((size_t)(bh >> 2) * T32_PER_B + head * 72) * Pn;
        float sp = 0.f;
        #pragma unroll
        for (int jj = 0; jj < 18; ++jj) sp += base[(q + 4 * jj) * Pn + p];
        part[q][p] = sp;
    }
    __syncthreads();
    if (t < Pn) hms[t] = part[0][t] + part[1][t] + part[2][t] + part[3][t];
    __syncthreads();

    // wmsum over this head's group
    float wsum = 0.f;
    for (int i = t; i < Gn; i += 256) wsum += wm[head * Gn + i];
    #pragma unroll
    for (int d = 1; d < 64; d <<= 1) wsum += __shfl_xor(wsum, d);
    if (l == 0) red[wv] = wsum;
    __syncthreads();
    wsum = red[0] + red[1] + red[2] + red[3];

    // logits[c] = sum_k w2[c,k]*hm[k] + b2[c]*wsum
    float lg = 0.f;
    #pragma unroll
    for (int k = 0; k < Pn; ++k) lg = fmaf(w2[t * Pn + k], hms[k], lg);
    lg = fmaf(b2[t], wsum, lg);

    // softmax over 256 channels
    float mx = lg;
    #pragma unroll
    for (int d = 1; d < 64; d <<= 1) mx = fmaxf(mx, __shfl_xor(mx, d));
    __syncthreads();
    if (l == 0) red[wv] = mx;
    __syncthreads();
    mx = fmaxf(fmaxf(red[0], red[1]), fmaxf(red[2], red[3]));
    const float ev = __expf(lg - mx);
    float sm = ev;
    #pragma unroll
    for (int d = 1; d < 64; d <<= 1) sm += __shfl_xor(sm, d);
    __syncthreads();
    if (l == 0) red[wv] = sm;
    __syncthreads();
    sm = red[0] + red[1] + red[2] + red[3];
    masks[t] = ev / sm;
    __syncthreads();

    // wmix[k] = sum_c mask[c]*w2[c,k]
    {
        const int k = t & (Pn - 1);
        const int q = t >> 6;
        float wp = 0.f;
        #pragma unroll
        for (int i = 0; i < 64; ++i) {
            const int c = q * 64 + i;
            wp = fmaf(masks[c], w2[c * Pn + k], wp);
        }
        part[q][k] = wp;
    }
    __syncthreads();
    if (t < Pn) wmix[bh * Pn + t] = part[0][t] + part[1][t] + part[2][t] + part[3][t];

    // bmix = sum_c mask[c]*b2[c]
    float bp = masks[t] * b2[t];
    #pragma unroll
    for (int d = 1; d < 64; d <<= 1) bp += __shfl_xor(bp, d);
    __syncthreads();
    if (l == 0) red[wv] = bp;
    __syncthreads();
    if (t == 0) bmix[bh] = red[0] + red[1] + red[2] + red[3];
}

// ---- K3: 128-s tiles. Phase1: ctx (all 256 lanes, 2/row). Phase2: 512B row bursts. ----
__global__ __launch_bounds__(256)
void k3_stream(const float* __restrict__ x, const short* __restrict__ hg,
               const float* __restrict__ wmix, const float* __restrict__ bmix,
               float* __restrict__ out)
{
    __shared__ float ctxl[ST3];

    const int bid  = blockIdx.x;
    const int b    = bid / T3_PER_B;
    const int st   = bid % T3_PER_B;
    const int s0   = st * ST3;              // 128-tiles never straddle heads (2304/128=18)
    const int head = s0 / Gn;
    const int bh   = b * HEADSn + head;
    const int t    = threadIdx.x;

    // ---- phase 1: ctx[r] = wmix . h[s0+r, :] + bmix; 2 threads per row ----
    {
        const int r    = t >> 1;            // 0..127
        const int half = t & 1;             // owns 32 of the 64 p
        const short* hr = hg + ((size_t)b * HWn + s0 + r) * Pn + half * 32;
        const float* wmx = wmix + bh * Pn + half * 32;
        float acc = 0.f;
        #pragma unroll
        for (int i = 0; i < 4; ++i) {
            const short8 v = *reinterpret_cast<const short8*>(hr + i * 8);
            const f32x4 w0 = *reinterpret_cast<const f32x4*>(wmx + i * 8);
            const f32x4 w1v = *reinterpret_cast<const f32x4*>(wmx + i * 8 + 4);
            #pragma unroll
            for (int j = 0; j < 4; ++j) {
                acc = fmaf(bf2f((unsigned short)v[j]), w0[j], acc);
                acc = fmaf(bf2f((unsigned short)v[4 + j]), w1v[j], acc);
            }
        }
        acc += __shfl_xor(acc, 1);
        if (half == 0) ctxl[r] = acc + bmix[bh];
    }
    __syncthreads();

    // ---- phase 2: out = x + ctx; 512B contiguous per c-row visit, 8 rows/pass ----
    const int c0 = t >> 5;                  // 0..7
    const int s8 = t & 31;                  // 0..31 -> 128 floats = 512B
    const f32x4 cv = *reinterpret_cast<const f32x4*>(&ctxl[s8 * 4]);
    const float* xb = x + (size_t)b * Cn * HWn + s0 + s8 * 4;
    float* ob = out + (size_t)b * Cn * HWn + s0 + s8 * 4;
    #pragma unroll
    for (int i = 0; i < 32; ++i) {
        const size_t off = (size_t)(c0 + 8 * i) * HWn;
        *reinterpret_cast<f32x4*>(ob + off) =
            *reinterpret_cast<const f32x4*>(xb + off) + cv;
    }
}

extern "C" void kernel_launch(void* const* d_in, const int* in_sizes, int n_in,
                              void* d_out, int out_size, void* d_ws, size_t ws_size,
                              hipStream_t stream)
{
    (void)in_sizes; (void)n_in; (void)out_size; (void)ws_size;
    const float* x     = (const float*)d_in[0];
    const float* w1    = (const float*)d_in[1];
    const float* b1    = (const float*)d_in[2];
    const float* gamma = (const float*)d_in[3];
    const float* beta  = (const float*)d_in[4];
    const float* mean  = (const float*)d_in[5];
    const float* var   = (const float*)d_in[6];
    const float* w2    = (const float*)d_in[7];
    const float* b2    = (const float*)d_in[8];
    const float* wm    = (const float*)d_in[9];
    // d_in[10] = bm: constant over softmax axis -> dropped

    float* out  = (float*)d_out;
    float* wsf  = (float*)d_ws;
    float* hmp  = wsf;                            // [4608*64] f32 tile partials
    float* wmix = hmp + NBLK1 * Pn;               // [64*64]
    float* bmix = wmix + Bn * HEADSn * Pn;        // [64]
    float* bcv  = bmix + 64;                      // [64]
    short* w1b  = (short*)(bcv + 64);             // [64*256] bf16 scale-folded
    short* hg   = w1b + Pn * Cn;                  // [16*9216*64] bf16

    k0_prep<<<dim3(8), dim3(256), 0, stream>>>(w1, b1, gamma, beta, mean, var, bcv, w1b);
    k1_gemm<<<dim3(NBLK1), dim3(128), 0, stream>>>(x, w1b, bcv, wm, hmp, hg);
    k2_mask<<<dim3(Bn * HEADSn), dim3(256), 0, stream>>>(hmp, w2, b2, wm, wmix, bmix);
    k3_stream<<<dim3(NBLK3), dim3(256), 0, stream>>>(x, hg, wmix, bmix, out);
}